// Round 5
// baseline (441.736 us; speedup 1.0000x reference)
//
#include <hip/hip_runtime.h>
#include <math.h>

#define MSZ 4096
#define ISZ 2048
#define NB   256                 // blocks: one 16-column slice each
#define NT   512                 // threads per block (8 waves)
#define NCOLS 16                 // output columns per block
#define ROWLANES 128             // NT/4: row-lanes in phase 1
#define RITER (ISZ / ROWLANES)   // 16 K-iterations per gate
#define OITER (MSZ / ROWLANES)   // 32 output-row iterations in phase 3

typedef float fx4 __attribute__((ext_vector_type(4)));

// ---------------------------------------------------------------------------
// Single fused kernel, NO grid sync needed: each block owns 16 output columns
// end-to-end.
//   phase 1: z[g][jslice] = sum_k x[k] * W_g[k][jslice]   (3 gates)
//            thread (cg=t&3, rl=t>>2) accumulates rows rl+128*i of float4-col
//            c4; wave shuffle-reduce over the 16 row-lanes in the wave, then
//            8 wave-partials land in 1.5 KB LDS.
//   phase 2: 16 threads apply bias + LSTM math -> h_t[jslice] in LDS.
//            h_t[j] = sigmoid(z_o)*tanh(sigmoid(z_i)*tanh(z_c))  (c0==0)
//   phase 3: out[:, jslice] = w_hid_out[:] * h_t[jslice], nontemporal stores.
// Traffic: 96 MB weights (each byte read once) + ~6 MB broadcast + 64 MB out.
// vs 3-kernel version: -2 dispatch nodes, -9 MB z_part round trip.
// Concurrency: 8 waves/CU x 16 batched dwordx4 in flight >> 9.4 KB/CU needed.
// ---------------------------------------------------------------------------
__global__ __launch_bounds__(NT) void k_lstm(
    const float* __restrict__ x,
    const float* __restrict__ w_inpgate,
    const float* __restrict__ w_outgate,
    const float* __restrict__ w_inp,
    const float* __restrict__ b_inpgate,
    const float* __restrict__ b_outgate,
    const float* __restrict__ b_inp,
    const float* __restrict__ w_hid_out,
    fx4* __restrict__ out4)
{
    const int b    = blockIdx.x;
    const int t    = threadIdx.x;
    const int cg   = t & 3;          // which float4-column group (0..3)
    const int rl   = t >> 2;         // row-lane (0..127)
    const int wave = t >> 6;         // 0..7
    const int lane = t & 63;
    const int jbase = b * NCOLS;
    const int c4    = (jbase >> 2) + cg;   // float4 column index in [0, MSZ/4)

    __shared__ float red[3][8][4][4];      // gate, wave, colgroup, elem (1.5 KB)
    __shared__ fx4   hsh4[4];              // h_t[jslice] as 4 float4s

    // Preload this thread's 16 x-values (reused across the 3 gates).
    float xr[RITER];
    #pragma unroll
    for (int i = 0; i < RITER; ++i) xr[i] = x[rl + ROWLANES * i];

    const float* Wg[3] = {w_inpgate, w_outgate, w_inp};

    #pragma unroll
    for (int g = 0; g < 3; ++g) {
        const fx4* W4 = (const fx4*)Wg[g];
        // Batch all 16 weight loads (64 VGPR) so they are all in flight.
        fx4 w[RITER];
        #pragma unroll
        for (int i = 0; i < RITER; ++i)
            w[i] = W4[(size_t)(rl + ROWLANES * i) * (MSZ / 4) + c4];

        fx4 a0 = {0.f, 0.f, 0.f, 0.f};
        fx4 a1 = {0.f, 0.f, 0.f, 0.f};
        #pragma unroll
        for (int i = 0; i < RITER; i += 2) {
            a0 += xr[i]     * w[i];
            a1 += xr[i + 1] * w[i + 1];
        }
        fx4 acc = a0 + a1;

        // Butterfly over lane bits 2..5 (the 16 row-lanes within this wave).
        #pragma unroll
        for (int s = 4; s <= 32; s <<= 1) {
            acc.x += __shfl_xor(acc.x, s);
            acc.y += __shfl_xor(acc.y, s);
            acc.z += __shfl_xor(acc.z, s);
            acc.w += __shfl_xor(acc.w, s);
        }
        if (lane < 4) {                    // lane == colgroup holds its sum
            red[g][wave][lane][0] = acc.x;
            red[g][wave][lane][1] = acc.y;
            red[g][wave][lane][2] = acc.z;
            red[g][wave][lane][3] = acc.w;
        }
    }
    __syncthreads();

    // ---- Phase 2: 16 threads -> h_t[jslice] --------------------------------
    if (t < NCOLS) {
        const int g4 = t >> 2, el = t & 3;
        float zi = b_inpgate[jbase + t];
        float zo = b_outgate[jbase + t];
        float zc = b_inp[jbase + t];
        #pragma unroll
        for (int wv = 0; wv < 8; ++wv) {
            zi += red[0][wv][g4][el];
            zo += red[1][wv][g4][el];
            zc += red[2][wv][g4][el];
        }
        const float ig  = 1.f / (1.f + __expf(-zi));
        const float og  = 1.f / (1.f + __expf(-zo));
        const float ct  = tanhf(zc);
        ((float*)hsh4)[t] = og * tanhf(ig * ct);   // forget*c0 == 0
    }
    __syncthreads();

    // ---- Phase 3: out[:, jslice] = w_hid_out[:] (outer) h_t[jslice] --------
    const fx4 hv = hsh4[cg];                       // broadcast within colgroup
    #pragma unroll 8
    for (int i = 0; i < OITER; ++i) {
        const int row = rl + ROWLANES * i;
        const float w = w_hid_out[row];            // L2-resident broadcast
        __builtin_nontemporal_store(w * hv, &out4[(size_t)row * (MSZ / 4) + c4]);
    }
}

extern "C" void kernel_launch(void* const* d_in, const int* in_sizes, int n_in,
                              void* d_out, int out_size, void* d_ws, size_t ws_size,
                              hipStream_t stream) {
    const float* x          = (const float*)d_in[0];
    // h0 = d_in[1], c0 = d_in[2]: zeros, unused (is_reset==1)
    const float* w_inpgate  = (const float*)d_in[3];
    const float* w_inp      = (const float*)d_in[6];
    const float* w_outgate  = (const float*)d_in[11];
    const float* w_hid_out  = (const float*)d_in[14];
    const float* b_inpgate  = (const float*)d_in[15];
    const float* b_inp      = (const float*)d_in[16];
    const float* b_outgate  = (const float*)d_in[18];

    k_lstm<<<NB, NT, 0, stream>>>(x, w_inpgate, w_outgate, w_inp,
                                  b_inpgate, b_outgate, b_inp,
                                  w_hid_out, (fx4*)d_out);
}